// Round 4
// baseline (112.403 us; speedup 1.0000x reference)
//
#include <hip/hip_runtime.h>
#include <math.h>

// knnLoss: B=4, N=8192, k=3. Brute-force 3-NN.
// R4: single fused kernel (partial+merge). 512 blocks x 256 threads.
//   - Block owns 64 sources (lane = source). 4 waves x 4 rounds cover the 16
//     target tiles: each round stages 4 tiles (2048 targets) into 4 LDS slots;
//     wave w processes slot w. Broadcast ds_read_b128 preserved per wave.
//   - Octet-min selection per tile (R3 machinery), exact fixup per tile into a
//     running exact triple in registers BEFORE the LDS slot is overwritten.
//     Exactness: global top-3 value => within-tile top-3 => its octet is a
//     top-3 octet-min of that tile => fixup inserts its exact value.
//   - No partial array, no merge kernel. Final: LDS merge across 4 waves,
//     wave-0 shuffle reduce, per-block atomicAdd + ticket finale.
//   - Workspace use = 64-byte header, zeroed by hipMemsetAsync (capturable).
#define BATCH 4
#define NPTS 8192
#define TILE 512
#define NTILES 16             // NPTS / TILE
#define SLOTS 4               // tiles staged per round (one per wave)
#define ROUNDS 4              // NTILES / SLOTS
#define SRC_PER_BLOCK 64
#define NBLOCKS (BATCH * NPTS / SRC_PER_BLOCK)  // 512
#define NOCT 64               // octets per tile
#define OCTF 36               // floats per padded octet (9 float4 = 144 B)
#define SLOTF (NOCT * OCTF)   // 2304 floats per LDS slot

typedef __attribute__((ext_vector_type(2))) float f2;

__device__ __forceinline__ float min3f(float a, float b, float c) {
    float d;
    asm("v_min3_f32 %0, %1, %2, %3" : "=v"(d) : "v"(a), "v"(b), "v"(c));
    return d;
}

// Branchless insert into sorted ascending triple; 4 ops via med3.
__device__ __forceinline__ void insert3(float d, float& a0, float& a1, float& a2) {
    float h = fmaxf(a1, d);
    float m = __builtin_amdgcn_fmed3f(a0, a1, d);
    a2 = fminf(a2, h);
    a1 = m;
    a0 = fminf(a0, d);
}

// Merge two sorted-ascending triples -> the sorted 3 smallest of the union.
__device__ __forceinline__ void merge33(float a0, float a1, float a2,
                                        float& b0, float& b1, float& b2) {
    float s0 = fminf(a0, b0);
    float h  = fmaxf(a0, b0);
    float m  = fminf(a1, b1);
    float mm = fminf(a2, b2);
    b1 = fminf(h, m);
    b2 = __builtin_amdgcn_fmed3f(h, m, mm);
    b0 = s0;
}

// Recompute the 8 exact p-values of one octet, insert into the exact chain.
__device__ __forceinline__ void octet_insert(const float4* ob, f2 nx, f2 ny, f2 nz,
                                             float& c0, float& c1, float& c2) {
    float4 X0 = ob[0], X1 = ob[1], Y0 = ob[2], Y1 = ob[3];
    float4 Z0 = ob[4], Z1 = ob[5], W0 = ob[6], W1 = ob[7];
    f2 pa = __builtin_elementwise_fma((f2){Z0.x, Z0.y}, nz, (f2){W0.x, W0.y});
    pa = __builtin_elementwise_fma((f2){Y0.x, Y0.y}, ny, pa);
    pa = __builtin_elementwise_fma((f2){X0.x, X0.y}, nx, pa);
    f2 pb = __builtin_elementwise_fma((f2){Z0.z, Z0.w}, nz, (f2){W0.z, W0.w});
    pb = __builtin_elementwise_fma((f2){Y0.z, Y0.w}, ny, pb);
    pb = __builtin_elementwise_fma((f2){X0.z, X0.w}, nx, pb);
    f2 pc = __builtin_elementwise_fma((f2){Z1.x, Z1.y}, nz, (f2){W1.x, W1.y});
    pc = __builtin_elementwise_fma((f2){Y1.x, Y1.y}, ny, pc);
    pc = __builtin_elementwise_fma((f2){X1.x, X1.y}, nx, pc);
    f2 pd = __builtin_elementwise_fma((f2){Z1.z, Z1.w}, nz, (f2){W1.z, W1.w});
    pd = __builtin_elementwise_fma((f2){Y1.z, Y1.w}, ny, pd);
    pd = __builtin_elementwise_fma((f2){X1.z, X1.w}, nx, pd);
    insert3(pa.x, c0, c1, c2);
    insert3(pa.y, c0, c1, c2);
    insert3(pb.x, c0, c1, c2);
    insert3(pb.y, c0, c1, c2);
    insert3(pc.x, c0, c1, c2);
    insert3(pc.y, c0, c1, c2);
    insert3(pd.x, c0, c1, c2);
    insert3(pd.y, c0, c1, c2);
}

__global__ __launch_bounds__(256) void knn_fused(const float* __restrict__ src,
                                                 const float* __restrict__ tgt,
                                                 float* __restrict__ acc,
                                                 float* __restrict__ cnt,
                                                 unsigned* __restrict__ ticket,
                                                 float* __restrict__ out) {
    __shared__ float tsf[SLOTS * SLOTF];  // 36864 B
    const int tid = threadIdx.x;
    const int lane = tid & 63, wave = tid >> 6;
    const int bid = blockIdx.x;
    const int gid = bid * SRC_PER_BLOCK + lane;  // flat source id (b*N + i)
    const int b = bid >> 7;                      // 128 blocks per batch, uniform

    // Source precompute (each wave loads its lane's source; 4x redundant, tiny).
    const float* sp = src + (size_t)gid * 3;
    float ax = sp[0], ay = sp[1], az = sp[2];
    f2 nx = (f2){-2.f * ax, -2.f * ax};
    f2 ny = (f2){-2.f * ay, -2.f * ay};
    f2 nz = (f2){-2.f * az, -2.f * az};

    float e0 = 3e38f, e1 = 3e38f, e2 = 3e38f;  // running exact triple (p-space)

    for (int r = 0; r < ROUNDS; ++r) {
        __syncthreads();  // prior round's LDS reads complete before overwrite
        // Stage 4 tiles = 2048 targets = 1024 pairs; pair p = j*256 + tid.
        #pragma unroll
        for (int j = 0; j < 4; ++j) {
            int p = j * 256 + tid;
            const float* tb = tgt + ((size_t)b * NPTS + r * (SLOTS * TILE) + 2 * p) * 3;
            float x0 = tb[0], y0 = tb[1], z0 = tb[2];
            float x1 = tb[3], y1 = tb[4], z1 = tb[5];
            float w0 = x0 * x0 + y0 * y0 + z0 * z0;
            float w1 = x1 * x1 + y1 * y1 + z1 * z1;
            if (!(x0 != 0.f || y0 != 0.f || z0 != 0.f)) w0 = 3.0e38f;
            if (!(x1 != 0.f || y1 != 0.f || z1 != 0.f)) w1 = 3.0e38f;
            int sl = p >> 8;           // LDS slot 0..3
            int o = (p >> 2) & 63;     // octet within tile
            int k = (2 * p) & 7;       // slot pair within octet
            int base = sl * SLOTF + o * OCTF + ((k >> 2) << 2) + (k & 3);
            *(float2*)(tsf + base)      = make_float2(x0, x1);
            *(float2*)(tsf + base + 8)  = make_float2(y0, y1);
            *(float2*)(tsf + base + 16) = make_float2(z0, z1);
            *(float2*)(tsf + base + 24) = make_float2(w0, w1);
        }
        __syncthreads();

        // Wave w processes LDS slot w (global tile 4r + w). Broadcast reads.
        const float4* tsv = (const float4*)(tsf + wave * SLOTF);
        float q0 = 3e38f, q1 = 3e38f, q2 = 3e38f;  // packed per-tile chain
        #pragma unroll 2
        for (int o = 0; o < NOCT; ++o) {
            float4 X0 = tsv[9 * o + 0], X1 = tsv[9 * o + 1];
            float4 Y0 = tsv[9 * o + 2], Y1 = tsv[9 * o + 3];
            float4 Z0 = tsv[9 * o + 4], Z1 = tsv[9 * o + 5];
            float4 W0 = tsv[9 * o + 6], W1 = tsv[9 * o + 7];
            f2 pa = __builtin_elementwise_fma((f2){Z0.x, Z0.y}, nz, (f2){W0.x, W0.y});
            pa = __builtin_elementwise_fma((f2){Y0.x, Y0.y}, ny, pa);
            pa = __builtin_elementwise_fma((f2){X0.x, X0.y}, nx, pa);
            f2 pb = __builtin_elementwise_fma((f2){Z0.z, Z0.w}, nz, (f2){W0.z, W0.w});
            pb = __builtin_elementwise_fma((f2){Y0.z, Y0.w}, ny, pb);
            pb = __builtin_elementwise_fma((f2){X0.z, X0.w}, nx, pb);
            f2 pc = __builtin_elementwise_fma((f2){Z1.x, Z1.y}, nz, (f2){W1.x, W1.y});
            pc = __builtin_elementwise_fma((f2){Y1.x, Y1.y}, ny, pc);
            pc = __builtin_elementwise_fma((f2){X1.x, X1.y}, nx, pc);
            f2 pd = __builtin_elementwise_fma((f2){Z1.z, Z1.w}, nz, (f2){W1.z, W1.w});
            pd = __builtin_elementwise_fma((f2){Y1.z, Y1.w}, ny, pd);
            pd = __builtin_elementwise_fma((f2){X1.z, X1.w}, nx, pd);
            float m1 = min3f(pa.x, pa.y, pb.x);
            float m2 = min3f(pb.y, pc.x, pc.y);
            float m3 = min3f(pd.x, pd.y, m1);
            float m4 = fminf(m2, m3);
            unsigned u = (__float_as_uint(m4) & 0xFFFFFFC0u) | (unsigned)o;
            insert3(__uint_as_float(u), q0, q1, q2);
        }
        // Per-tile exact fixup (before this slot is overwritten next round).
        octet_insert(tsv + 9 * (int)(__float_as_uint(q0) & 63u), nx, ny, nz, e0, e1, e2);
        octet_insert(tsv + 9 * (int)(__float_as_uint(q1) & 63u), nx, ny, nz, e0, e1, e2);
        octet_insert(tsv + 9 * (int)(__float_as_uint(q2) & 63u), nx, ny, nz, e0, e1, e2);
    }

    // Cross-wave merge via LDS (reuse tsf; 768 floats needed).
    __syncthreads();
    tsf[wave * 64 + lane]       = e0;
    tsf[256 + wave * 64 + lane] = e1;
    tsf[512 + wave * 64 + lane] = e2;
    __syncthreads();

    if (tid < 64) {
        float a0 = tsf[lane], a1 = tsf[256 + lane], a2 = tsf[512 + lane];
        #pragma unroll
        for (int g = 1; g < 4; ++g)
            merge33(tsf[g * 64 + lane], tsf[256 + g * 64 + lane],
                    tsf[512 + g * 64 + lane], a0, a1, a2);

        bool valid = (ax != 0.f) || (ay != 0.f) || (az != 0.f);
        float qq = ax * ax + ay * ay + az * az;  // deferred |s|^2
        float s = valid ? (sqrtf(fmaxf(a0 + qq, 0.f)) + sqrtf(fmaxf(a1 + qq, 0.f)) +
                           sqrtf(fmaxf(a2 + qq, 0.f)))
                        : 0.f;
        float c = valid ? 1.f : 0.f;

        // Single-wave reduction (threads 0..63 are wave 0).
        for (int off = 32; off >= 1; off >>= 1) {
            s += __shfl_down(s, off);
            c += __shfl_down(c, off);
        }
        if (lane == 0) {
            atomicAdd(&acc[b], s);
            atomicAdd(&cnt[b], c);
            __threadfence();
            unsigned t = atomicAdd(ticket, 1u);
            if (t == (unsigned)(NBLOCKS - 1)) {
                float loss = 0.f;
                #pragma unroll
                for (int bb = 0; bb < BATCH; ++bb) {
                    float as = atomicAdd(&acc[bb], 0.f);
                    float ac = atomicAdd(&cnt[bb], 0.f);
                    loss += as / (ac * 3.0f);
                }
                out[0] = loss * (1.0f / BATCH);
            }
        }
    }
}

extern "C" void kernel_launch(void* const* d_in, const int* in_sizes, int n_in,
                              void* d_out, int out_size, void* d_ws, size_t ws_size,
                              hipStream_t stream) {
    const float* src = (const float*)d_in[0];
    const float* tgt = (const float*)d_in[1];
    float* out = (float*)d_out;

    // ws header: [0,16) acc[4]; [16,32) cnt[4]; [32,36) ticket
    float* acc = (float*)d_ws;
    float* cnt = acc + 4;
    unsigned* ticket = (unsigned*)((char*)d_ws + 32);

    hipMemsetAsync(d_ws, 0, 64, stream);  // zero header (graph-capturable)
    knn_fused<<<dim3(NBLOCKS), 256, 0, stream>>>(src, tgt, acc, cnt, ticket, out);
}